// Round 10
// baseline (316.996 us; speedup 1.0000x reference)
//
#include <hip/hip_runtime.h>
#include <stdint.h>

// CapsuleLayer dynamic routing, MI355X. fp32 in/out.
// B=256, N=10, I=1152, D=16, K(Din)=8, ROUTINGS=3.
// R10: request-coalescing fix. u layout = [n][i][b][d] with 16-b tiles in
// every wave (lane = bq*4+dq): W reads 16-lane-shared, u stores/loads fully
// contiguous 512 B per wave-instr. R9's 50M one-line requests -> ~8M.
// Sweep0 partials in registers (no shfl); single reusable partial buffer.

#define BN 256
#define NN 10
#define II 1152
#define DD 16
#define KK 8
#define IQ 32          // i per block
#define NQ (II / IQ)   // 36 chunks

typedef unsigned short ushort_t;
typedef unsigned int uint_t;

__device__ __forceinline__ float bflo(uint_t u) {
    union { uint_t i; float f; } v; v.i = u << 16; return v.f;
}
__device__ __forceinline__ float bfhi(uint_t u) {
    union { uint_t i; float f; } v; v.i = u & 0xffff0000u; return v.f;
}
__device__ __forceinline__ uint_t f2bf(float f) {  // RTNE bf16
    union { float f; uint_t i; } v; v.f = f;
    uint_t x = v.i;
    return (x + 0x7fffu + ((x >> 16) & 1u)) >> 16;
}

// ---------------- K1 + sweep0 partials --------------------------------------
// block = (i-chunk of 32, b-tile of 16). 256 thr = 4 waves; wave = 16 bq x 4 dq.
// wave wv handles i = iq*32 + s*4 + wv, s = 0..7 serial.
// W[n][i] row shared by 16 bq-lanes; u store contiguous 512 B/wave.
// part0[b][iq][n*16+d] = 0.1 * sum_{i in chunk} u (register accum, LDS merge).
__global__ __launch_bounds__(256) void caps_uhat_s0(const float* __restrict__ xg,
                                                    const float* __restrict__ wg,
                                                    ushort_t* __restrict__ u,
                                                    float* __restrict__ part0,
                                                    int b0, int C, int nbt)
{
    __shared__ float red[64 * 4 * 41];  // [(wv*16+bq)*4+dq][n*4+j] pad 41, 42 KB-> 41*256*4=42KB? (64*4*41*4B = 42.0 KB)
    const int tid = threadIdx.x;
    const int lane = tid & 63, wv = tid >> 6;
    const int dq = lane & 3, bq = lane >> 2;
    const int iq = blockIdx.x / nbt;
    const int bl = (blockIdx.x % nbt) * 16;    // chunk-local b base
    const int bG = b0 + bl + bq;               // global b for x / part0

    float sp[NN][4];
#pragma unroll
    for (int n = 0; n < NN; ++n)
#pragma unroll
        for (int j = 0; j < 4; ++j) sp[n][j] = 0.f;

    for (int s = 0; s < 8; ++s) {
        const int i = iq * IQ + s * 4 + wv;
        const float4* xp = (const float4*)(xg + ((size_t)bG * II + i) * KK);
        float4 x0 = xp[0], x1 = xp[1];
        float xv[8];
        xv[0] = x0.x; xv[1] = x0.y; xv[2] = x0.z; xv[3] = x0.w;
        xv[4] = x1.x; xv[5] = x1.y; xv[6] = x1.z; xv[7] = x1.w;

#pragma unroll
        for (int n = 0; n < NN; ++n) {
            const float4* wp = (const float4*)(wg + (size_t)(n * II + i) * (DD * KK)) + dq * 8;
            float4 w0 = wp[0], w1 = wp[1], w2 = wp[2], w3 = wp[3];
            float4 w4 = wp[4], w5 = wp[5], w6 = wp[6], w7 = wp[7];
            float s4[4];
            s4[0] = w0.x * xv[0] + w0.y * xv[1] + w0.z * xv[2] + w0.w * xv[3]
                  + w1.x * xv[4] + w1.y * xv[5] + w1.z * xv[6] + w1.w * xv[7];
            s4[1] = w2.x * xv[0] + w2.y * xv[1] + w2.z * xv[2] + w2.w * xv[3]
                  + w3.x * xv[4] + w3.y * xv[5] + w3.z * xv[6] + w3.w * xv[7];
            s4[2] = w4.x * xv[0] + w4.y * xv[1] + w4.z * xv[2] + w4.w * xv[3]
                  + w5.x * xv[4] + w5.y * xv[5] + w5.z * xv[6] + w5.w * xv[7];
            s4[3] = w6.x * xv[0] + w6.y * xv[1] + w6.z * xv[2] + w6.w * xv[3]
                  + w7.x * xv[4] + w7.y * xv[5] + w7.z * xv[6] + w7.w * xv[7];
#pragma unroll
            for (int j = 0; j < 4; ++j) sp[n][j] += s4[j];
            uint2 q;
            q.x = f2bf(s4[0]) | (f2bf(s4[1]) << 16);
            q.y = f2bf(s4[2]) | (f2bf(s4[3]) << 16);
            *(uint2*)(u + ((size_t)(n * II + i) * C + bl + bq) * DD + dq * 4) = q;
        }
    }

    // epilogue: per-lane 40 values -> LDS (2-way max banks) -> 4-wave sum
    float* rr = &red[((wv * 16 + bq) * 4 + dq) * 41];
#pragma unroll
    for (int n = 0; n < NN; ++n)
#pragma unroll
        for (int j = 0; j < 4; ++j) rr[n * 4 + j] = sp[n][j];
    __syncthreads();
    for (int v = tid; v < 16 * 160; v += 256) {
        int b = v / 160, r = v - b * 160;
        int n = r >> 4, d = r & 15, dqq = d >> 2, j = d & 3;
        float acc = 0.f;
#pragma unroll
        for (int w = 0; w < 4; ++w)
            acc += red[((w * 16 + b) * 4 + dqq) * 41 + n * 4 + j];
        part0[((size_t)(b0 + bl + b) * NQ + iq) * 160 + r] = 0.1f * acc;
    }
}

// ---------------- caps_o<NP>: o[b] (+)= squash(sum_p part[b][p]) ------------
template <int NP>
__global__ __launch_bounds__(192) void caps_o(const float* __restrict__ part,
                                              float* __restrict__ o,
                                              int b0, int mode)
{
    const int b = b0 + blockIdx.x;
    const int t = threadIdx.x;
    if (t < 160) {
        float v = 0.f;
#pragma unroll
        for (int p = 0; p < NP; ++p)
            v += part[((size_t)b * NP + p) * 160 + t];
        float sq = v * v;
#pragma unroll
        for (int m = 1; m <= 8; m <<= 1) sq += __shfl_xor(sq, m, 64);
        float val = v * (sqrtf(sq) / (1.0f + sq));
        if (mode) o[(size_t)b * 160 + t] += val;
        else      o[(size_t)b * 160 + t]  = val;
    }
}

// ---------------- sweep r=1,2 ----------------------------------------------
// block = (i-chunk of 32, b-tile of 16); wave = 16 bq x 4 dq; u reads
// contiguous 512 B/instr. o in 40 regs/lane. softmax reduce = 2 shfl (dq bits).
__global__ __launch_bounds__(256) void caps_sweep(const ushort_t* __restrict__ u,
                                                  const float* __restrict__ og,
                                                  float* __restrict__ pout,
                                                  int b0, int C, int nbt)
{
    __shared__ float red[64 * 4 * 41];
    const int tid = threadIdx.x;
    const int lane = tid & 63, wv = tid >> 6;
    const int dq = lane & 3, bq = lane >> 2;
    const int iq = blockIdx.x / nbt;
    const int bl = (blockIdx.x % nbt) * 16;
    const int bG = b0 + bl + bq;

    float o4[NN][4];
#pragma unroll
    for (int n = 0; n < NN; ++n) {
        float4 t4 = *(const float4*)(og + (size_t)bG * 160 + n * 16 + dq * 4);
        o4[n][0] = t4.x; o4[n][1] = t4.y; o4[n][2] = t4.z; o4[n][3] = t4.w;
    }

    float sp[NN][4];
#pragma unroll
    for (int n = 0; n < NN; ++n)
#pragma unroll
        for (int j = 0; j < 4; ++j) sp[n][j] = 0.f;

    for (int s = 0; s < 8; ++s) {
        const int i = iq * IQ + s * 4 + wv;
        uint2 r[NN];
#pragma unroll
        for (int n = 0; n < NN; ++n)
            r[n] = *(const uint2*)(u + ((size_t)(n * II + i) * C + bl + bq) * DD + dq * 4);

        float a[NN];
#pragma unroll
        for (int n = 0; n < NN; ++n) {
            float p = bflo(r[n].x) * o4[n][0] + bfhi(r[n].x) * o4[n][1]
                    + bflo(r[n].y) * o4[n][2] + bfhi(r[n].y) * o4[n][3];
            float t2 = p + __shfl_xor(p, 1, 64);
            a[n] = t2 + __shfl_xor(t2, 2, 64);
        }
        float m = a[0];
#pragma unroll
        for (int n = 1; n < NN; ++n) m = fmaxf(m, a[n]);
        float c[NN], ssum = 0.f;
#pragma unroll
        for (int n = 0; n < NN; ++n) { c[n] = __expf(a[n] - m); ssum += c[n]; }
        float inv = 1.0f / ssum;
#pragma unroll
        for (int n = 0; n < NN; ++n) {
            float w = c[n] * inv;
            sp[n][0] += w * bflo(r[n].x); sp[n][1] += w * bfhi(r[n].x);
            sp[n][2] += w * bflo(r[n].y); sp[n][3] += w * bfhi(r[n].y);
        }
    }

    float* rr = &red[((wv * 16 + bq) * 4 + dq) * 41];
#pragma unroll
    for (int n = 0; n < NN; ++n)
#pragma unroll
        for (int j = 0; j < 4; ++j) rr[n * 4 + j] = sp[n][j];
    __syncthreads();
    for (int v = tid; v < 16 * 160; v += 256) {
        int b = v / 160, r2 = v - b * 160;
        int n = r2 >> 4, d = r2 & 15, dqq = d >> 2, j = d & 3;
        float acc = 0.f;
#pragma unroll
        for (int w = 0; w < 4; ++w)
            acc += red[((w * 16 + b) * 4 + dqq) * 41 + n * 4 + j];
        pout[((size_t)(b0 + bl + b) * NQ + iq) * 160 + r2] = acc;
    }
}

extern "C" void kernel_launch(void* const* d_in, const int* in_sizes, int n_in,
                              void* d_out, int out_size, void* d_ws, size_t ws_size,
                              hipStream_t stream)
{
    const float* xg = (const float*)d_in[0];  // [B,I,K]
    const float* wg = (const float*)d_in[1];  // [N,I,D,K]
    if (n_in >= 2 && in_sizes[0] == NN * II * DD * KK) {
        const float* t = xg; xg = wg; wg = t;
    }
    float* outp = (float*)d_out;

    const size_t perB  = (size_t)NN * II * DD * 2;   // 368,640 B bf16 u per b
    const size_t partB = (size_t)BN * NQ * 160 * 4;  // 5,898,240 (single, reused)
    const size_t oB    = (size_t)BN * 160 * 4;       // 163,840
    size_t extra = partB + oB;
    size_t avail = (ws_size > extra) ? ws_size - extra : 0;
    int C = 256;
    if (avail < (size_t)256 * perB) {
        C = (int)(avail / perB);
        C &= ~15;
        if (C < 16) C = 16;
    }
    ushort_t* uws = (ushort_t*)d_ws;
    float* part = (float*)((char*)d_ws + (size_t)C * perB);
    float* ovec = part + (size_t)BN * NQ * 160;

    for (int b0 = 0; b0 < BN; b0 += C) {
        int c = (BN - b0 < C) ? (BN - b0) : C;
        int nbt = c / 16;
        caps_uhat_s0<<<NQ * nbt, 256, 0, stream>>>(xg, wg, uws, part, b0, c, nbt);
        caps_o<NQ>  <<<c, 192, 0, stream>>>(part, ovec, b0, 0);
        caps_sweep  <<<NQ * nbt, 256, 0, stream>>>(uws, ovec, part, b0, c, nbt);
        caps_o<NQ>  <<<c, 192, 0, stream>>>(part, ovec, b0, 1);
        caps_sweep  <<<NQ * nbt, 256, 0, stream>>>(uws, ovec, part, b0, c, nbt);
        caps_o<NQ>  <<<c, 192, 0, stream>>>(part, outp, b0, 0);
    }
}